// Round 1
// baseline (633.320 us; speedup 1.0000x reference)
//
#include <hip/hip_runtime.h>

#define TWOPI 6.28318530717958647692f

#define BB 2
#define CC 32
#define NN 8192
#define MH 864                      // 12*12*6 retained modes
#define XFT_FLOATS (BB*MH*CC*2)     // 110592
#define NCH 64                      // split-K chunks for forward

__device__ __forceinline__ float2 cmul(float2 a, float2 b){
    return make_float2(fmaf(a.x, b.x, -(a.y*b.y)), fmaf(a.x, b.y, a.y*b.x));
}

// ---------------- weight transpose: wt[q][abz][i][o][2] ----------------
__global__ __launch_bounds__(256)
void wtrans_kernel(const float* __restrict__ w1, const float* __restrict__ w2,
                   const float* __restrict__ w3, const float* __restrict__ w4,
                   float* __restrict__ wt){
    const int abz = blockIdx.x;       // 0..215  (a*36 + b*6 + z)
    const int q   = blockIdx.y;       // 0..3
    const float* w = (q==0)?w1:(q==1)?w2:(q==2)?w3:w4;
    const int tid = threadIdx.x;
    #pragma unroll
    for (int k=0;k<4;k++){
        int iop = tid + k*256;        // (i*32+o) in 0..1023
        float2 v = *(const float2*)(w + ((size_t)iop*216 + abz)*2);
        *(float2*)(wt + (((size_t)q*216 + abz)*1024 + iop)*2) = v;
    }
}

// ---------------- forward NUFFT: xft[b][m][c][2] (split-K partials) ----------------
// grid (NCH, 9, B), block 128 = 16 columns x 8 cslots(4 ch each)
template<bool ATOMIC>
__global__ __launch_bounds__(128, 2)
void fwd_kernel(const float* __restrict__ x, const float* __restrict__ pos,
                float* __restrict__ dst){
    const int tid = threadIdx.x;
    const int colslot = tid & 15;
    const int cs = tid >> 4;                  // 0..7
    const int col = blockIdx.y * 16 + colslot; // 0..143  (= ix*12 + iy)
    const int ixm = col / 12;
    const int iym = col % 12;
    const int b   = blockIdx.z;
    const int nch = blockIdx.x;
    const int nb0 = nch * (NN / NCH);         // chunk of 128 points

    __shared__ float2 exl[12][65];
    __shared__ float2 eyl[12][65];
    __shared__ float2 ezt[64][8];
    __shared__ float  xl[CC][68];

    float acc[6][4][2];
    #pragma unroll
    for (int z=0;z<6;z++)
      #pragma unroll
      for (int j=0;j<4;j++){ acc[z][j][0]=0.f; acc[z][j][1]=0.f; }

    for (int t=0; t<2; ++t){
        const int nb = nb0 + t*64;
        __syncthreads();
        if (tid < 64){
            const int n = nb + tid;
            const float px = pos[((size_t)b*NN + n)*3 + 0];
            const float py = pos[((size_t)b*NN + n)*3 + 1];
            const float pz = pos[((size_t)b*NN + n)*3 + 2];
            float s, c;
            float2 pw[7];
            // forward phase: exp(-i*2pi*k*p); e1 = exp(-i*2pi*p)
            sincosf(TWOPI*px, &s, &c);
            { float2 e1 = make_float2(c, -s);
              pw[0] = make_float2(1.f, 0.f);
              #pragma unroll
              for (int k=1;k<7;k++) pw[k] = cmul(pw[k-1], e1);
              #pragma unroll
              for (int k=0;k<6;k++) exl[k][tid] = pw[k];
              #pragma unroll
              for (int k=6;k<12;k++) exl[k][tid] = make_float2(pw[12-k].x, -pw[12-k].y);
            }
            sincosf(TWOPI*py, &s, &c);
            { float2 e1 = make_float2(c, -s);
              pw[0] = make_float2(1.f, 0.f);
              #pragma unroll
              for (int k=1;k<7;k++) pw[k] = cmul(pw[k-1], e1);
              #pragma unroll
              for (int k=0;k<6;k++) eyl[k][tid] = pw[k];
              #pragma unroll
              for (int k=6;k<12;k++) eyl[k][tid] = make_float2(pw[12-k].x, -pw[12-k].y);
            }
            sincosf(TWOPI*pz, &s, &c);
            { float2 e1 = make_float2(c, -s);
              float2 qv = make_float2(1.f, 0.f);
              #pragma unroll
              for (int k=0;k<6;k++){ ezt[tid][k] = qv; qv = cmul(qv, e1); }
            }
        }
        #pragma unroll
        for (int k=0;k<4;k++){
            int v = tid + k*128;
            int c = v >> 4;
            int j = v & 15;
            float4 xv = *(const float4*)(x + (size_t)(b*CC + c)*NN + nb + j*4);
            *(float4*)(&xl[c][j*4]) = xv;
        }
        __syncthreads();

        #pragma unroll 2
        for (int np=0; np<64; ++np){
            float2 rex = exl[ixm][np];
            float2 rey = eyl[iym][np];
            float2 exy = cmul(rex, rey);
            float xv0 = xl[cs*4+0][np];
            float xv1 = xl[cs*4+1][np];
            float xv2 = xl[cs*4+2][np];
            float xv3 = xl[cs*4+3][np];
            const float4* ezp = (const float4*)(&ezt[np][0]);
            float4 ea = ezp[0], eb2 = ezp[1], ec = ezp[2];
            float2 ezv[6];
            ezv[0] = make_float2(ea.x, ea.y);  ezv[1] = make_float2(ea.z, ea.w);
            ezv[2] = make_float2(eb2.x, eb2.y); ezv[3] = make_float2(eb2.z, eb2.w);
            ezv[4] = make_float2(ec.x, ec.y);  ezv[5] = make_float2(ec.z, ec.w);
            #pragma unroll
            for (int z=0; z<6; ++z){
                float2 ph = cmul(exy, ezv[z]);
                acc[z][0][0] = fmaf(ph.x, xv0, acc[z][0][0]);
                acc[z][0][1] = fmaf(ph.y, xv0, acc[z][0][1]);
                acc[z][1][0] = fmaf(ph.x, xv1, acc[z][1][0]);
                acc[z][1][1] = fmaf(ph.y, xv1, acc[z][1][1]);
                acc[z][2][0] = fmaf(ph.x, xv2, acc[z][2][0]);
                acc[z][2][1] = fmaf(ph.y, xv2, acc[z][2][1]);
                acc[z][3][0] = fmaf(ph.x, xv3, acc[z][3][0]);
                acc[z][3][1] = fmaf(ph.y, xv3, acc[z][3][1]);
            }
        }
    }

    const int c0 = cs*4;
    if (ATOMIC){
        #pragma unroll
        for (int z=0;z<6;z++)
          #pragma unroll
          for (int j=0;j<4;j++){
            float* p = dst + (((size_t)b*MH + col*6 + z)*CC + c0 + j)*2;
            atomicAdd(p+0, acc[z][j][0]);
            atomicAdd(p+1, acc[z][j][1]);
          }
    } else {
        float* base = dst + (size_t)nch*XFT_FLOATS;
        #pragma unroll
        for (int z=0;z<6;z++)
          #pragma unroll
          for (int j=0;j<4;j++){
            *(float2*)(base + (((size_t)b*MH + col*6 + z)*CC + c0 + j)*2)
                = make_float2(acc[z][j][0], acc[z][j][1]);
          }
    }
}

// ---------------- split-K reduce ----------------
__global__ __launch_bounds__(256)
void reduce_kernel(const float* __restrict__ part, float* __restrict__ xft){
    const int i = blockIdx.x*256 + threadIdx.x;   // 110592 = 432*256
    float s = 0.f;
    #pragma unroll 8
    for (int k=0;k<NCH;k++) s += part[(size_t)k*XFT_FLOATS + i];
    xft[i] = s;
}

// ---------------- spectral mix + hermitian channel fold: T[b][m][c<16][2] ----------------
// grid (108, B), block 256 = 8 modes x 32 out-channels
__global__ __launch_bounds__(256)
void mix_kernel(const float* __restrict__ xft, const float* __restrict__ wt,
                float* __restrict__ T){
    const int tid = threadIdx.x;
    const int o  = tid & 31;
    const int ml = tid >> 5;      // 0..7
    const int b  = blockIdx.y;
    const int m0 = blockIdx.x * 8;

    __shared__ float xs[512];
    __shared__ float os[8][32][2];

    const float* xb = xft + ((size_t)b*MH + m0)*64;
    xs[tid]     = xb[tid];
    xs[tid+256] = xb[tid+256];
    __syncthreads();

    const int m  = m0 + ml;
    const int ix = m / 72;
    const int iy = (m / 6) % 12;
    const int iz = m % 6;
    const int q  = (ix>=6 ? 1 : 0) + (iy>=6 ? 2 : 0);   // w1,w2,w3,w4
    const int a  = ix % 6;
    const int bb2 = iy % 6;
    const int abz = (a*6 + bb2)*6 + iz;
    const float* wq = wt + ((size_t)q*216 + abz)*2048;

    float orr = 0.f, oii = 0.f;
    #pragma unroll 8
    for (int i=0;i<32;i++){
        float xr = xs[ml*64 + i*2];
        float xi = xs[ml*64 + i*2 + 1];
        float2 wv = *(const float2*)(wq + (i*32 + o)*2);
        orr = fmaf(xr, wv.x, orr); orr = fmaf(-xi, wv.y, orr);
        oii = fmaf(xr, wv.y, oii); oii = fmaf( xi, wv.x, oii);
    }
    os[ml][o][0] = orr;
    os[ml][o][1] = oii;
    __syncthreads();
    if (o < 16){
        float tr = os[ml][o][0] + os[ml][31-o][0];
        float ti = os[ml][o][1] + os[ml][31-o][1];
        *(float2*)(T + (((size_t)b*MH + m)*16 + o)*2) = make_float2(tr, ti);
    }
}

// ---------------- inverse NUFFT: y[b][c][n] = (2/N)*Re sum_m ph*T ----------------
// grid (128, 2, B), block 256 = 64 n x 4 waves (4 folded channels each)
__global__ __launch_bounds__(256, 2)
void inv_kernel(const float* __restrict__ pos, const float* __restrict__ T,
                float* __restrict__ y){
    const int tid = threadIdx.x;
    const int nl  = tid & 63;
    const int cs  = tid >> 6;          // wave id -> channel group (uniform)
    const int b   = blockIdx.z;
    const int ixh = blockIdx.y;        // ix-half: 0 -> ix 0..5, 1 -> ix 6..11
    const int n0  = blockIdx.x * 64;

    __shared__ float2 exl[6][64];
    __shared__ float2 eyl[12][64];
    __shared__ float2 ezl[6][64];

    if (tid < 64){
        const int n = n0 + tid;
        const float px = pos[((size_t)b*NN + n)*3 + 0];
        const float py = pos[((size_t)b*NN + n)*3 + 1];
        const float pz = pos[((size_t)b*NN + n)*3 + 2];
        float s, c;
        float2 pw[7];
        // inverse phase: exp(+i*2pi*k*p); e1 = exp(+i*2pi*p)
        sincosf(TWOPI*px, &s, &c);
        { float2 e1 = make_float2(c, s);
          pw[0] = make_float2(1.f, 0.f);
          #pragma unroll
          for (int k=1;k<7;k++) pw[k] = cmul(pw[k-1], e1);
          if (ixh == 0){
            #pragma unroll
            for (int k=0;k<6;k++) exl[k][tid] = pw[k];
          } else {
            // ix = 6+k -> kx = k-6 -> conj(e1^(6-k))
            #pragma unroll
            for (int k=0;k<6;k++) exl[k][tid] = make_float2(pw[6-k].x, -pw[6-k].y);
          }
        }
        sincosf(TWOPI*py, &s, &c);
        { float2 e1 = make_float2(c, s);
          pw[0] = make_float2(1.f, 0.f);
          #pragma unroll
          for (int k=1;k<7;k++) pw[k] = cmul(pw[k-1], e1);
          #pragma unroll
          for (int k=0;k<6;k++) eyl[k][tid] = pw[k];
          #pragma unroll
          for (int k=6;k<12;k++) eyl[k][tid] = make_float2(pw[12-k].x, -pw[12-k].y);
        }
        sincosf(TWOPI*pz, &s, &c);
        { float2 e1 = make_float2(c, s);
          float2 qv = make_float2(1.f, 0.f);
          #pragma unroll
          for (int k=0;k<6;k++){ ezl[k][tid] = qv; qv = cmul(qv, e1); }
        }
    }
    __syncthreads();

    const int c0 = __builtin_amdgcn_readfirstlane(cs) * 4;   // wave-uniform
    const float* Tb = T + (size_t)b*MH*32 + (size_t)c0*2;
    float a0=0.f, a1=0.f, a2=0.f, a3=0.f;

    for (int ix6=0; ix6<6; ++ix6){
        float2 rex = exl[ix6][nl];
        for (int iy=0; iy<12; ++iy){
            float2 rey = eyl[iy][nl];
            float2 exy = cmul(rex, rey);
            const float* tp = Tb + (size_t)(((ixh*6 + ix6)*12 + iy)*6)*32;
            #pragma unroll
            for (int iz=0; iz<6; ++iz){
                float2 rez = ezl[iz][nl];
                float2 ph = cmul(exy, rez);
                float4 t01 = *(const float4*)(tp + iz*32);
                float4 t23 = *(const float4*)(tp + iz*32 + 4);
                a0 = fmaf(ph.x, t01.x, fmaf(-ph.y, t01.y, a0));
                a1 = fmaf(ph.x, t01.z, fmaf(-ph.y, t01.w, a1));
                a2 = fmaf(ph.x, t23.x, fmaf(-ph.y, t23.y, a2));
                a3 = fmaf(ph.x, t23.z, fmaf(-ph.y, t23.w, a3));
            }
        }
    }

    const float sc2 = 2.0f / (float)NN;
    const int n = n0 + nl;
    float* yb = y + (size_t)b*CC*NN + n;
    atomicAdd(yb + (size_t)(c0+0)*NN, a0*sc2);
    atomicAdd(yb + (size_t)(c0+1)*NN, a1*sc2);
    atomicAdd(yb + (size_t)(c0+2)*NN, a2*sc2);
    atomicAdd(yb + (size_t)(c0+3)*NN, a3*sc2);
    atomicAdd(yb + (size_t)(31-(c0+0))*NN, a0*sc2);
    atomicAdd(yb + (size_t)(31-(c0+1))*NN, a1*sc2);
    atomicAdd(yb + (size_t)(31-(c0+2))*NN, a2*sc2);
    atomicAdd(yb + (size_t)(31-(c0+3))*NN, a3*sc2);
}

extern "C" void kernel_launch(void* const* d_in, const int* in_sizes, int n_in,
                              void* d_out, int out_size, void* d_ws, size_t ws_size,
                              hipStream_t stream){
    const float* x   = (const float*)d_in[0];
    const float* pos = (const float*)d_in[1];
    const float* w1  = (const float*)d_in[2];
    const float* w2  = (const float*)d_in[3];
    const float* w3  = (const float*)d_in[4];
    const float* w4  = (const float*)d_in[5];
    float* out = (float*)d_out;
    char* wsb = (char*)d_ws;

    // ws layout (bytes):
    float* wt   = (float*)(wsb);                 // 4*216*1024*2*4 = 7,077,888
    float* xft  = (float*)(wsb + 7077888);       // 110592*4      =   442,368
    float* T    = (float*)(wsb + 7520256);       // 2*864*16*2*4  =   221,184
    float* part = (float*)(wsb + 7741440);       // 64*110592*4   = 28,311,552
    const bool use_part = (ws_size >= 36052992ull);

    wtrans_kernel<<<dim3(216,4), 256, 0, stream>>>(w1, w2, w3, w4, wt);

    if (use_part){
        fwd_kernel<false><<<dim3(NCH,9,2), 128, 0, stream>>>(x, pos, part);
        reduce_kernel<<<dim3(432), 256, 0, stream>>>(part, xft);
    } else {
        hipMemsetAsync(xft, 0, 442368, stream);
        fwd_kernel<true><<<dim3(NCH,9,2), 128, 0, stream>>>(x, pos, xft);
    }

    mix_kernel<<<dim3(108,2), 256, 0, stream>>>(xft, wt, T);

    hipMemsetAsync(out, 0, (size_t)out_size*sizeof(float), stream);
    inv_kernel<<<dim3(128,2,2), 256, 0, stream>>>(pos, T, out);
}

// Round 2
// 118.629 us; speedup vs baseline: 5.3387x; 5.3387x over previous
//
#include <hip/hip_runtime.h>

#define TWOPI 6.28318530717958647692f

#define BB 2
#define CC 32
#define NN 8192
#define MH 864                      // 12*12*6 retained modes
#define XFT_FLOATS (BB*MH*CC*2)     // 110592
#define NCH 64                      // split-K chunks for forward

__device__ __forceinline__ float2 cmul(float2 a, float2 b){
    return make_float2(fmaf(a.x, b.x, -(a.y*b.y)), fmaf(a.x, b.y, a.y*b.x));
}

// ---------------- weight transpose: wt[q][abz][i][o][2] ----------------
__global__ __launch_bounds__(256)
void wtrans_kernel(const float* __restrict__ w1, const float* __restrict__ w2,
                   const float* __restrict__ w3, const float* __restrict__ w4,
                   float* __restrict__ wt){
    const int abz = blockIdx.x;       // 0..215  (a*36 + b*6 + z)
    const int q   = blockIdx.y;       // 0..3
    const float* w = (q==0)?w1:(q==1)?w2:(q==2)?w3:w4;
    const int tid = threadIdx.x;
    #pragma unroll
    for (int k=0;k<4;k++){
        int iop = tid + k*256;        // (i*32+o) in 0..1023
        float2 v = *(const float2*)(w + ((size_t)iop*216 + abz)*2);
        *(float2*)(wt + (((size_t)q*216 + abz)*1024 + iop)*2) = v;
    }
}

// ---------------- forward NUFFT: xft[b][m][c][2] (split-K partials) ----------------
// grid (NCH, 9, B), block 128 = 16 columns x 8 cslots(4 ch each)
template<bool ATOMIC>
__global__ __launch_bounds__(128, 2)
void fwd_kernel(const float* __restrict__ x, const float* __restrict__ pos,
                float* __restrict__ dst){
    const int tid = threadIdx.x;
    const int colslot = tid & 15;
    const int cs = tid >> 4;                  // 0..7
    const int col = blockIdx.y * 16 + colslot; // 0..143  (= ix*12 + iy)
    const int ixm = col / 12;
    const int iym = col % 12;
    const int b   = blockIdx.z;
    const int nch = blockIdx.x;
    const int nb0 = nch * (NN / NCH);         // chunk of 128 points

    __shared__ float2 exl[12][65];
    __shared__ float2 eyl[12][65];
    __shared__ float2 ezt[64][8];
    __shared__ float  xl[CC][68];

    float acc[6][4][2];
    #pragma unroll
    for (int z=0;z<6;z++)
      #pragma unroll
      for (int j=0;j<4;j++){ acc[z][j][0]=0.f; acc[z][j][1]=0.f; }

    for (int t=0; t<2; ++t){
        const int nb = nb0 + t*64;
        __syncthreads();
        if (tid < 64){
            const int n = nb + tid;
            const float px = pos[((size_t)b*NN + n)*3 + 0];
            const float py = pos[((size_t)b*NN + n)*3 + 1];
            const float pz = pos[((size_t)b*NN + n)*3 + 2];
            float s, c;
            float2 pw[7];
            // forward phase: exp(-i*2pi*k*p); e1 = exp(-i*2pi*p)
            sincosf(TWOPI*px, &s, &c);
            { float2 e1 = make_float2(c, -s);
              pw[0] = make_float2(1.f, 0.f);
              #pragma unroll
              for (int k=1;k<7;k++) pw[k] = cmul(pw[k-1], e1);
              #pragma unroll
              for (int k=0;k<6;k++) exl[k][tid] = pw[k];
              #pragma unroll
              for (int k=6;k<12;k++) exl[k][tid] = make_float2(pw[12-k].x, -pw[12-k].y);
            }
            sincosf(TWOPI*py, &s, &c);
            { float2 e1 = make_float2(c, -s);
              pw[0] = make_float2(1.f, 0.f);
              #pragma unroll
              for (int k=1;k<7;k++) pw[k] = cmul(pw[k-1], e1);
              #pragma unroll
              for (int k=0;k<6;k++) eyl[k][tid] = pw[k];
              #pragma unroll
              for (int k=6;k<12;k++) eyl[k][tid] = make_float2(pw[12-k].x, -pw[12-k].y);
            }
            sincosf(TWOPI*pz, &s, &c);
            { float2 e1 = make_float2(c, -s);
              float2 qv = make_float2(1.f, 0.f);
              #pragma unroll
              for (int k=0;k<6;k++){ ezt[tid][k] = qv; qv = cmul(qv, e1); }
            }
        }
        #pragma unroll
        for (int k=0;k<4;k++){
            int v = tid + k*128;
            int c = v >> 4;
            int j = v & 15;
            float4 xv = *(const float4*)(x + (size_t)(b*CC + c)*NN + nb + j*4);
            *(float4*)(&xl[c][j*4]) = xv;
        }
        __syncthreads();

        #pragma unroll 2
        for (int np=0; np<64; ++np){
            float2 rex = exl[ixm][np];
            float2 rey = eyl[iym][np];
            float2 exy = cmul(rex, rey);
            float xv0 = xl[cs*4+0][np];
            float xv1 = xl[cs*4+1][np];
            float xv2 = xl[cs*4+2][np];
            float xv3 = xl[cs*4+3][np];
            const float4* ezp = (const float4*)(&ezt[np][0]);
            float4 ea = ezp[0], eb2 = ezp[1], ec = ezp[2];
            float2 ezv[6];
            ezv[0] = make_float2(ea.x, ea.y);  ezv[1] = make_float2(ea.z, ea.w);
            ezv[2] = make_float2(eb2.x, eb2.y); ezv[3] = make_float2(eb2.z, eb2.w);
            ezv[4] = make_float2(ec.x, ec.y);  ezv[5] = make_float2(ec.z, ec.w);
            #pragma unroll
            for (int z=0; z<6; ++z){
                float2 ph = cmul(exy, ezv[z]);
                acc[z][0][0] = fmaf(ph.x, xv0, acc[z][0][0]);
                acc[z][0][1] = fmaf(ph.y, xv0, acc[z][0][1]);
                acc[z][1][0] = fmaf(ph.x, xv1, acc[z][1][0]);
                acc[z][1][1] = fmaf(ph.y, xv1, acc[z][1][1]);
                acc[z][2][0] = fmaf(ph.x, xv2, acc[z][2][0]);
                acc[z][2][1] = fmaf(ph.y, xv2, acc[z][2][1]);
                acc[z][3][0] = fmaf(ph.x, xv3, acc[z][3][0]);
                acc[z][3][1] = fmaf(ph.y, xv3, acc[z][3][1]);
            }
        }
    }

    const int c0 = cs*4;
    if (ATOMIC){
        #pragma unroll
        for (int z=0;z<6;z++)
          #pragma unroll
          for (int j=0;j<4;j++){
            float* p = dst + (((size_t)b*MH + col*6 + z)*CC + c0 + j)*2;
            atomicAdd(p+0, acc[z][j][0]);
            atomicAdd(p+1, acc[z][j][1]);
          }
    } else {
        float* base = dst + (size_t)nch*XFT_FLOATS;
        #pragma unroll
        for (int z=0;z<6;z++)
          #pragma unroll
          for (int j=0;j<4;j++){
            *(float2*)(base + (((size_t)b*MH + col*6 + z)*CC + c0 + j)*2)
                = make_float2(acc[z][j][0], acc[z][j][1]);
          }
    }
}

// ---------------- split-K reduce ----------------
__global__ __launch_bounds__(256)
void reduce_kernel(const float* __restrict__ part, float* __restrict__ xft){
    const int i = blockIdx.x*256 + threadIdx.x;   // 110592 = 432*256
    float s = 0.f;
    #pragma unroll 8
    for (int k=0;k<NCH;k++) s += part[(size_t)k*XFT_FLOATS + i];
    xft[i] = s;
}

// ---------------- spectral mix + hermitian channel fold: T[b][m][c<16][2] ----------------
// grid (108, B), block 256 = 8 modes x 32 out-channels
__global__ __launch_bounds__(256)
void mix_kernel(const float* __restrict__ xft, const float* __restrict__ wt,
                float* __restrict__ T){
    const int tid = threadIdx.x;
    const int o  = tid & 31;
    const int ml = tid >> 5;      // 0..7
    const int b  = blockIdx.y;
    const int m0 = blockIdx.x * 8;

    __shared__ float xs[512];
    __shared__ float os[8][32][2];

    const float* xb = xft + ((size_t)b*MH + m0)*64;
    xs[tid]     = xb[tid];
    xs[tid+256] = xb[tid+256];
    __syncthreads();

    const int m  = m0 + ml;
    const int ix = m / 72;
    const int iy = (m / 6) % 12;
    const int iz = m % 6;
    const int q  = (ix>=6 ? 1 : 0) + (iy>=6 ? 2 : 0);   // w1,w2,w3,w4
    const int a  = ix % 6;
    const int bb2 = iy % 6;
    const int abz = (a*6 + bb2)*6 + iz;
    const float* wq = wt + ((size_t)q*216 + abz)*2048;

    float orr = 0.f, oii = 0.f;
    #pragma unroll 8
    for (int i=0;i<32;i++){
        float xr = xs[ml*64 + i*2];
        float xi = xs[ml*64 + i*2 + 1];
        float2 wv = *(const float2*)(wq + (i*32 + o)*2);
        orr = fmaf(xr, wv.x, orr); orr = fmaf(-xi, wv.y, orr);
        oii = fmaf(xr, wv.y, oii); oii = fmaf( xi, wv.x, oii);
    }
    os[ml][o][0] = orr;
    os[ml][o][1] = oii;
    __syncthreads();
    if (o < 16){
        float tr = os[ml][o][0] + os[ml][31-o][0];
        float ti = os[ml][o][1] + os[ml][31-o][1];
        *(float2*)(T + (((size_t)b*MH + m)*16 + o)*2) = make_float2(tr, ti);
    }
}

// ---------------- inverse NUFFT (no atomics) ----------------
// y[b][c][n] = y[b][31-c][n] = (2/N)*Re sum_m ph[m,n]*T[m,c]
// grid (NN/64, B), block 512 = 8 waves x 64 n-lanes.
// Wave w accumulates (ix,iy) pairs [w*18, w*18+18) over all iz into acc[16],
// then LDS tree-reduce across waves, plain coalesced stores.
__global__ __launch_bounds__(512, 4)
void inv_kernel(const float* __restrict__ pos, const float* __restrict__ T,
                float* __restrict__ y){
    const int tid = threadIdx.x;
    const int nl  = tid & 63;
    const int b   = blockIdx.y;
    const int n0  = blockIdx.x * 64;

    __shared__ float2 exl[12][64];
    __shared__ float2 eyl[12][64];
    __shared__ float2 ezl[6][64];
    __shared__ float  red[8][16][64];

    if (tid < 64){
        const int n = n0 + tid;
        const float px = pos[((size_t)b*NN + n)*3 + 0];
        const float py = pos[((size_t)b*NN + n)*3 + 1];
        const float pz = pos[((size_t)b*NN + n)*3 + 2];
        float s, c;
        float2 pw[7];
        // inverse phase: exp(+i*2pi*k*p); e1 = exp(+i*2pi*p)
        sincosf(TWOPI*px, &s, &c);
        { float2 e1 = make_float2(c, s);
          pw[0] = make_float2(1.f, 0.f);
          #pragma unroll
          for (int k=1;k<7;k++) pw[k] = cmul(pw[k-1], e1);
          #pragma unroll
          for (int k=0;k<6;k++) exl[k][tid] = pw[k];
          // ix = k in 6..11 -> kx = k-12 -> conj(e1^(12-k))
          #pragma unroll
          for (int k=6;k<12;k++) exl[k][tid] = make_float2(pw[12-k].x, -pw[12-k].y);
        }
        sincosf(TWOPI*py, &s, &c);
        { float2 e1 = make_float2(c, s);
          pw[0] = make_float2(1.f, 0.f);
          #pragma unroll
          for (int k=1;k<7;k++) pw[k] = cmul(pw[k-1], e1);
          #pragma unroll
          for (int k=0;k<6;k++) eyl[k][tid] = pw[k];
          #pragma unroll
          for (int k=6;k<12;k++) eyl[k][tid] = make_float2(pw[12-k].x, -pw[12-k].y);
        }
        sincosf(TWOPI*pz, &s, &c);
        { float2 e1 = make_float2(c, s);
          float2 qv = make_float2(1.f, 0.f);
          #pragma unroll
          for (int k=0;k<6;k++){ ezl[k][tid] = qv; qv = cmul(qv, e1); }
        }
    }
    __syncthreads();

    const int w = __builtin_amdgcn_readfirstlane(tid >> 6);   // wave id, uniform
    float acc[16];
    #pragma unroll
    for (int c=0;c<16;c++) acc[c] = 0.f;

    const float* Tb = T + (size_t)b*MH*32;
    for (int p=0; p<18; ++p){
        const int pp = w*18 + p;            // (ix,iy) pair, wave-uniform
        const int ix = pp / 12;
        const int iy = pp % 12;
        float2 exy = cmul(exl[ix][nl], eyl[iy][nl]);
        const float* tp = Tb + (size_t)pp*6*32;
        #pragma unroll
        for (int iz=0; iz<6; ++iz){
            float2 ph = cmul(exy, ezl[iz][nl]);
            const float4* tv4 = (const float4*)(tp + iz*32);
            #pragma unroll
            for (int q=0;q<8;q++){
                float4 tv = tv4[q];          // (Tr[2q], Ti[2q], Tr[2q+1], Ti[2q+1])
                acc[2*q]   = fmaf(ph.x, tv.x, fmaf(-ph.y, tv.y, acc[2*q]));
                acc[2*q+1] = fmaf(ph.x, tv.z, fmaf(-ph.y, tv.w, acc[2*q+1]));
            }
        }
    }

    #pragma unroll
    for (int c=0;c<16;c++) red[w][c][nl] = acc[c];
    __syncthreads();

    const float sc2 = 2.0f / (float)NN;
    #pragma unroll
    for (int t=0;t<2;t++){
        int oidx = tid + t*512;             // 0..1023 = c*64 + nn
        int c  = oidx >> 6;                 // 0..15
        int nn = oidx & 63;
        float s = 0.f;
        #pragma unroll
        for (int w2=0; w2<8; ++w2) s += red[w2][c][nn];
        s *= sc2;
        y[(size_t)b*CC*NN + (size_t)c*NN + n0 + nn]      = s;
        y[(size_t)b*CC*NN + (size_t)(31-c)*NN + n0 + nn] = s;
    }
}

extern "C" void kernel_launch(void* const* d_in, const int* in_sizes, int n_in,
                              void* d_out, int out_size, void* d_ws, size_t ws_size,
                              hipStream_t stream){
    const float* x   = (const float*)d_in[0];
    const float* pos = (const float*)d_in[1];
    const float* w1  = (const float*)d_in[2];
    const float* w2  = (const float*)d_in[3];
    const float* w3  = (const float*)d_in[4];
    const float* w4  = (const float*)d_in[5];
    float* out = (float*)d_out;
    char* wsb = (char*)d_ws;

    // ws layout (bytes):
    float* wt   = (float*)(wsb);                 // 4*216*1024*2*4 = 7,077,888
    float* xft  = (float*)(wsb + 7077888);       // 110592*4      =   442,368
    float* T    = (float*)(wsb + 7520256);       // 2*864*16*2*4  =   221,184
    float* part = (float*)(wsb + 7741440);       // 64*110592*4   = 28,311,552
    const bool use_part = (ws_size >= 36052992ull);

    wtrans_kernel<<<dim3(216,4), 256, 0, stream>>>(w1, w2, w3, w4, wt);

    if (use_part){
        fwd_kernel<false><<<dim3(NCH,9,2), 128, 0, stream>>>(x, pos, part);
        reduce_kernel<<<dim3(432), 256, 0, stream>>>(part, xft);
    } else {
        hipMemsetAsync(xft, 0, 442368, stream);
        fwd_kernel<true><<<dim3(NCH,9,2), 128, 0, stream>>>(x, pos, xft);
    }

    mix_kernel<<<dim3(108,2), 256, 0, stream>>>(xft, wt, T);

    inv_kernel<<<dim3(128,2), 512, 0, stream>>>(pos, T, out);
}